// Round 9
// baseline (214.546 us; speedup 1.0000x reference)
//
#include <hip/hip_runtime.h>
#include <hip/hip_bf16.h>

namespace {

typedef __attribute__((ext_vector_type(8))) short short8;
typedef __attribute__((ext_vector_type(4))) short s16x4;
typedef __attribute__((ext_vector_type(4))) float f32x4;

constexpr int H = 128;
constexpr int N = 200;
constexpr int BN = 1600;          // B*N
constexpr int X_SIZE = BN * H;    // 204800
constexpr int NH = N * H;         // 25600
constexpr int NT = 13;            // j-tiles of 16

// ws offsets (floats)
constexpr int WS_VX    = 0;
constexpr int WS_UX    = WS_VX + X_SIZE;
constexpr int WS_VXN   = WS_UX + X_SIZE;
constexpr int WS_ESUMS = WS_VXN + X_SIZE;      // 32 slots x H
constexpr int WS_ESSQS = WS_ESUMS + 32 * H;
constexpr int WS_NSUMS = WS_ESSQS + 32 * H;
constexpr int WS_NSSQS = WS_NSUMS + 32 * H;
constexpr int WS_STAT_END = WS_NSSQS + 32 * H;
constexpr int WS_ESC   = WS_STAT_END;
constexpr int WS_ESH   = WS_ESC + H;
constexpr int WS_NSC   = WS_ESH + H;
constexpr int WS_NSH   = WS_NSC + H;
constexpr int WS_EBF   = WS_NSH + H;           // bf16 fragment buffer
// frag layout: slab = (bi*13 + jt)*4 + s ; 512 shorts per slab (64 lanes x 8)
constexpr size_t EBF_SHORTS = (size_t)BN * NT * 4 * 512;
constexpr size_t NEED_WS_BYTES = (size_t)WS_EBF * 4 + EBF_SHORTS * 2;

__device__ __forceinline__ unsigned short f2bf(float f) {
  __hip_bfloat16 h = __float2bfloat16(f);
  return __builtin_bit_cast(unsigned short, h);
}

__device__ __forceinline__ short8 pack8(f32x4 a, f32x4 b) {
  short8 r;
  r[0] = (short)f2bf(a[0]); r[1] = (short)f2bf(a[1]);
  r[2] = (short)f2bf(a[2]); r[3] = (short)f2bf(a[3]);
  r[4] = (short)f2bf(b[0]); r[5] = (short)f2bf(b[1]);
  r[6] = (short)f2bf(b[2]); r[7] = (short)f2bf(b[3]);
  return r;
}

__device__ __forceinline__ f32x4 bf4f(s16x4 v) {
  f32x4 r;
  r[0] = __uint_as_float(((unsigned)(unsigned short)v[0]) << 16);
  r[1] = __uint_as_float(((unsigned)(unsigned short)v[1]) << 16);
  r[2] = __uint_as_float(((unsigned)(unsigned short)v[2]) << 16);
  r[3] = __uint_as_float(((unsigned)(unsigned short)v[3]) << 16);
  return r;
}

// ---- node linears: Vx, Ux, Vxn (masked) ----
__global__ __launch_bounds__(128) void k_prep(
    const float* __restrict__ x, const int* __restrict__ mask,
    const float* __restrict__ VeW, const float* __restrict__ Veb,
    const float* __restrict__ UnW, const float* __restrict__ Unb,
    const float* __restrict__ VnW, const float* __restrict__ Vnb,
    float* __restrict__ ws) {
  const int bi = blockIdx.x, h = threadIdx.x;
  __shared__ float xr[H];
  xr[h] = x[bi * H + h];
  __syncthreads();
  const float mi = (float)mask[bi];
  float a0 = 0.f, a1 = 0.f, a2 = 0.f;
  #pragma unroll 4
  for (int k = 0; k < H; k += 4) {
    const float x0 = xr[k], x1 = xr[k + 1], x2 = xr[k + 2], x3 = xr[k + 3];
    float4 w;
    w = *(const float4*)&VeW[h * H + k];
    a0 += w.x * x0 + w.y * x1 + w.z * x2 + w.w * x3;
    w = *(const float4*)&UnW[h * H + k];
    a1 += w.x * x0 + w.y * x1 + w.z * x2 + w.w * x3;
    w = *(const float4*)&VnW[h * H + k];
    a2 += w.x * x0 + w.y * x1 + w.z * x2 + w.w * x3;
  }
  ws[WS_VX  + bi * H + h] = mi * (a0 + Veb[h]);
  ws[WS_UX  + bi * H + h] = mi * (a1 + Unb[h]);
  ws[WS_VXN + bi * H + h] = mi * (a2 + Vnb[h]);
}

// ---- pass 0: GEMM + edge stats + agg + x_tmp (round-8 proven pipeline) ----
// STORE=1 additionally exports packed bf16 E-fragments (1 store/wave/tile)
// to ws for the barrier-free pass 1; waits re-peeled for the extra store.
template <int STORE>
__global__ __launch_bounds__(256, 3) void k_edge0(
    const float* __restrict__ e, const int* __restrict__ mask,
    const float* __restrict__ UeW, const float* __restrict__ Ueb,
    float* __restrict__ ws, unsigned short* __restrict__ ebf,
    float* __restrict__ outx) {
  const int bi = blockIdx.x;
  const int b = bi / N;
  const int tid = threadIdx.x;
  const int w = tid >> 6, lane = tid & 63;
  const int l15 = lane & 15, lg = lane >> 4;
  const int hbase = w * 32;

  __shared__ float lds[2][3 * 2048];   // [buf][e | vx | vxn], 48 KB
  __shared__ float mrow[N];
  __shared__ float sS[H], sS2[H], sA[H];

  const float mi = (float)mask[bi];
  const float* __restrict__ eg  = e + (size_t)bi * NH;
  const float* __restrict__ vxg = ws + WS_VX  + (size_t)b * NH;
  const float* __restrict__ vng = ws + WS_VXN + (size_t)b * NH;

  auto stage = [&](int buf, int jt) {
    const int j0 = jt * 16;
    #pragma unroll
    for (int ii = 0; ii < 2; ++ii) {
      const int instr = 2 * w + ii;               // 0..7
      const int row = 2 * instr + (lane >> 5);    // 0..15
      const int gr = min(j0 + row, N - 1);
      const int sc16 = (lane & 31) ^ (row & 7);   // swizzled 16B chunk
      const size_t so = (size_t)gr * H + sc16 * 4;
      float* dst = &lds[buf][instr * 256];
      __builtin_amdgcn_global_load_lds(
          (const __attribute__((address_space(1))) void*)(eg + so),
          (__attribute__((address_space(3))) void*)dst, 16, 0, 0);
      __builtin_amdgcn_global_load_lds(
          (const __attribute__((address_space(1))) void*)(vxg + so),
          (__attribute__((address_space(3))) void*)(dst + 2048), 16, 0, 0);
      __builtin_amdgcn_global_load_lds(
          (const __attribute__((address_space(1))) void*)(vng + so),
          (__attribute__((address_space(3))) void*)(dst + 4096), 16, 0, 0);
    }
  };

  if (tid < N) mrow[tid] = (float)mask[b * N + tid];

  short8 Wf[2][4];   // A-operand: lane holds W[hbase+ht*16+l15][s*32 + lg*8 + 0..7]
  #pragma unroll
  for (int ht = 0; ht < 2; ++ht) {
    const float* wr = &UeW[(size_t)(hbase + ht * 16 + l15) * H + lg * 8];
    #pragma unroll
    for (int s = 0; s < 4; ++s) {
      const f32x4 u0 = *(const f32x4*)(wr + s * 32);
      const f32x4 u1 = *(const f32x4*)(wr + s * 32 + 4);
      Wf[ht][s] = pack8(u0, u1);
    }
  }
  f32x4 base4[2];
  #pragma unroll
  for (int ht = 0; ht < 2; ++ht) {
    const int h0 = hbase + ht * 16 + 4 * lg;
    const f32x4 ub = *(const f32x4*)&Ueb[h0];
    const f32x4 vx = *(const f32x4*)&ws[WS_VX + (size_t)bi * H + h0];
    base4[ht] = ub + vx;
  }

  asm volatile("s_waitcnt vmcnt(0) lgkmcnt(0)" ::: "memory");
  __builtin_amdgcn_s_barrier();     // mrow visible; vmcnt clean

  stage(0, 0);
  stage(1, 1);

  float bnS[2][4] = {{0,0,0,0},{0,0,0,0}};
  float bnS2[2][4] = {{0,0,0,0},{0,0,0,0}};
  float ag[2][4] = {{0,0,0,0},{0,0,0,0}};

  for (int jt = 0; jt < NT; ++jt) {
    // FIFO peel. STORE=0: [S_jt, S_jt+1] steady. STORE=1 adds 1 st/tile:
    //  jt=0:[S0 S1]->6  jt=1:[S1 S2 st0]->7  2..11:[S_jt st S_jt+1 st]->8
    //  jt=12:[S12 st10 st11]->2
    if constexpr (STORE) {
      if (jt == 0)      asm volatile("s_waitcnt vmcnt(6)" ::: "memory");
      else if (jt == 1) asm volatile("s_waitcnt vmcnt(7)" ::: "memory");
      else if (jt < 12) asm volatile("s_waitcnt vmcnt(8)" ::: "memory");
      else              asm volatile("s_waitcnt vmcnt(2)" ::: "memory");
    } else {
      if (jt < 12) asm volatile("s_waitcnt vmcnt(6)" ::: "memory");
      else         asm volatile("s_waitcnt vmcnt(0)" ::: "memory");
    }
    __builtin_amdgcn_s_barrier();    // all waves' stage(jt) landed

    const float* tp = &lds[jt & 1][0];
    short8 Ef[4];                    // B-operand: col j = l15, k = lg*8 + s*32 + 0..7
    #pragma unroll
    for (int s = 0; s < 4; ++s) {
      const int c0 = (lg * 2 + s * 8) ^ (l15 & 7);
      const int c1 = (lg * 2 + s * 8 + 1) ^ (l15 & 7);
      const f32x4 u0 = *(const f32x4*)&tp[l15 * 128 + c0 * 4];
      const f32x4 u1 = *(const f32x4*)&tp[l15 * 128 + c1 * 4];
      Ef[s] = pack8(u0, u1);
    }
    f32x4 vx4[2], vn4[2];
    #pragma unroll
    for (int ht = 0; ht < 2; ++ht) {
      const int h0 = hbase + ht * 16 + 4 * lg;
      const int ch = (h0 >> 2) ^ (l15 & 7);
      vx4[ht] = *(const f32x4*)&tp[2048 + l15 * 128 + ch * 4];
      vn4[ht] = *(const f32x4*)&tp[4096 + l15 * 128 + ch * 4];
    }

    asm volatile("s_waitcnt lgkmcnt(0)" ::: "memory");
    __builtin_amdgcn_sched_barrier(0);
    __builtin_amdgcn_s_barrier();    // all waves done reading lds[jt&1]

    if (jt + 2 < NT) stage(jt & 1, jt + 2);
    __builtin_amdgcn_sched_barrier(0);
    if constexpr (STORE) {
      // export packed frags: wave w stores slice s=w (uniform branch, 1 vmem)
      unsigned short* fb =
          ebf + (((size_t)bi * NT + jt) * 4 + w) * 512 + (size_t)lane * 8;
      if (w == 0)      *(short8*)fb = Ef[0];
      else if (w == 1) *(short8*)fb = Ef[1];
      else if (w == 2) *(short8*)fb = Ef[2];
      else             *(short8*)fb = Ef[3];
    }
    __builtin_amdgcn_sched_barrier(0);

    f32x4 acc[2] = {f32x4(0.f), f32x4(0.f)};
    #pragma unroll
    for (int s = 0; s < 4; ++s) {
      #pragma unroll
      for (int ht = 0; ht < 2; ++ht)   // D[h][j]: col j = l15, row h = hbase+ht*16+4*lg+r
        acc[ht] = __builtin_amdgcn_mfma_f32_16x16x32_bf16(Wf[ht][s], Ef[s], acc[ht], 0, 0, 0);
    }

    const int j = jt * 16 + l15;
    const float msk = (j < N) ? mi * mrow[j < N ? j : 0] : 0.f;
    #pragma unroll
    for (int ht = 0; ht < 2; ++ht) {
      #pragma unroll
      for (int r = 0; r < 4; ++r) {
        const float v = acc[ht][r] + base4[ht][r] + vx4[ht][r];
        bnS[ht][r]  += msk * v;
        bnS2[ht][r] += msk * v * v;
        const float sg = __builtin_amdgcn_rcpf(1.f + __expf(-v));
        ag[ht][r] += msk * sg * vn4[ht][r];
      }
    }
  }

  #pragma unroll
  for (int ht = 0; ht < 2; ++ht) {
    #pragma unroll
    for (int r = 0; r < 4; ++r) {
      #pragma unroll
      for (int mm = 1; mm <= 8; mm <<= 1) {
        bnS[ht][r]  += __shfl_xor(bnS[ht][r], mm);
        bnS2[ht][r] += __shfl_xor(bnS2[ht][r], mm);
        ag[ht][r]   += __shfl_xor(ag[ht][r], mm);
      }
    }
  }
  if (l15 == 0) {
    #pragma unroll
    for (int ht = 0; ht < 2; ++ht) {
      #pragma unroll
      for (int r = 0; r < 4; ++r) {
        const int h = hbase + ht * 16 + 4 * lg + r;
        sS[h] = bnS[ht][r]; sS2[h] = bnS2[ht][r]; sA[h] = ag[ht][r];
      }
    }
  }
  __syncthreads();
  if (tid < H) {
    const int slot = (bi & 31) * H + tid;
    atomicAdd(&ws[WS_ESUMS + slot], sS[tid]);
    atomicAdd(&ws[WS_ESSQS + slot], sS2[tid]);
    // x_tmp = Ux + agg -> stored into out[0:X_SIZE]; node BN partials
    const float v = ws[WS_UX + (size_t)bi * H + tid] + sA[tid];
    outx[(size_t)bi * H + tid] = v;
    atomicAdd(&ws[WS_NSUMS + slot], mi * v);
    atomicAdd(&ws[WS_NSSQS + slot], mi * v * v);
  }
}

// ---- counts + finalize BN scale/shift for edge and node ----
__global__ void k_stats(const int* __restrict__ mask,
                        const float* __restrict__ beg, const float* __restrict__ beb,
                        const float* __restrict__ bng, const float* __restrict__ bnb,
                        float* __restrict__ ws) {
  __shared__ float sb[8];
  const int t = threadIdx.x;          // 256 threads
  const int b = t >> 5, li = t & 31;
  float s = 0.f;
  for (int i = li; i < N; i += 32) s += (float)mask[b * N + i];
  #pragma unroll
  for (int o = 16; o >= 1; o >>= 1) s += __shfl_down(s, o, 32);
  if (li == 0) sb[b] = s;
  __syncthreads();
  if (t < H) {
    float cn = 0.f, ce = 0.f;
    #pragma unroll
    for (int bb = 0; bb < 8; ++bb) { cn += sb[bb]; ce += sb[bb] * sb[bb]; }
    ce = fmaxf(ce, 1.f); cn = fmaxf(cn, 1.f);
    float es = 0.f, es2 = 0.f, ns = 0.f, ns2 = 0.f;
    #pragma unroll 4
    for (int k = 0; k < 32; ++k) {
      es  += ws[WS_ESUMS + k * H + t];
      es2 += ws[WS_ESSQS + k * H + t];
      ns  += ws[WS_NSUMS + k * H + t];
      ns2 += ws[WS_NSSQS + k * H + t];
    }
    const float me = es / ce;
    const float ve = fmaxf(es2 / ce - me * me, 0.f);
    const float se = rsqrtf(ve + 1e-5f) * beg[t];
    ws[WS_ESC + t] = se;
    ws[WS_ESH + t] = beb[t] - me * se;
    const float mn = ns / cn;
    const float vn = fmaxf(ns2 / cn - mn * mn, 0.f);
    const float sn = rsqrtf(vn + 1e-5f) * bng[t];
    ws[WS_NSC + t] = sn;
    ws[WS_NSH + t] = bnb[t] - mn * sn;
  }
}

// ---- x_new = x + relu(masked BN(x_tmp)); x_tmp lives in out[0:X_SIZE] ----
__global__ void k_x2(const float* __restrict__ x, const int* __restrict__ mask,
                     const float* __restrict__ ws, float* __restrict__ out) {
  const int idx = blockIdx.x * 256 + threadIdx.x;
  if (idx >= X_SIZE) return;
  const int h = idx & 127, bi = idx >> 7;
  const float v = out[idx];
  const float r = (mask[bi] != 0) ? (v * ws[WS_NSC + h] + ws[WS_NSH + h]) : v;
  out[idx] = x[idx] + fmaxf(r, 0.f);
}

// ---- pass 1 (fast): barrier-free, LDS-free; E-frags + residual from ebf ----
#define P1_ISSUE(t, E0, E1, E2, E3, R0, R1, VX0, VX1, MJ)                    \
  {                                                                          \
    const size_t slab = ((size_t)bi * NT + (t)) * 4;                         \
    const unsigned short* fb = ebf + slab * 512 + (size_t)lane * 8;          \
    E0 = *(const short8*)(fb);                                               \
    E1 = *(const short8*)(fb + 512);                                         \
    E2 = *(const short8*)(fb + 1024);                                        \
    E3 = *(const short8*)(fb + 1536);                                        \
    const int jc = min((t) * 16 + l15, N - 1);                               \
    MJ = mask[b * N + jc];                                                   \
    const size_t vrow = WS_VX + (size_t)(b * N + jc) * H;                    \
    VX0 = *(const f32x4*)&ws[vrow + h0a];                                    \
    VX1 = *(const f32x4*)&ws[vrow + h0b];                                    \
    const unsigned short* rb = ebf + (slab + w) * 512;                       \
    R0 = *(const s16x4*)(rb + (lgp * 16 + l15) * 8 + eo);                    \
    R1 = *(const s16x4*)(rb + ((lgp + 2) * 16 + l15) * 8 + eo);              \
  }

#define P1_TILE(t, E0, E1, E2, E3, R0, R1, VX0, VX1, MJ)                     \
  {                                                                          \
    f32x4 acc0 = {0.f, 0.f, 0.f, 0.f}, acc1 = {0.f, 0.f, 0.f, 0.f};         \
    acc0 = __builtin_amdgcn_mfma_f32_16x16x32_bf16(Wf[0][0], E0, acc0, 0, 0, 0); \
    acc1 = __builtin_amdgcn_mfma_f32_16x16x32_bf16(Wf[1][0], E0, acc1, 0, 0, 0); \
    acc0 = __builtin_amdgcn_mfma_f32_16x16x32_bf16(Wf[0][1], E1, acc0, 0, 0, 0); \
    acc1 = __builtin_amdgcn_mfma_f32_16x16x32_bf16(Wf[1][1], E1, acc1, 0, 0, 0); \
    acc0 = __builtin_amdgcn_mfma_f32_16x16x32_bf16(Wf[0][2], E2, acc0, 0, 0, 0); \
    acc1 = __builtin_amdgcn_mfma_f32_16x16x32_bf16(Wf[1][2], E2, acc1, 0, 0, 0); \
    acc0 = __builtin_amdgcn_mfma_f32_16x16x32_bf16(Wf[0][3], E3, acc0, 0, 0, 0); \
    acc1 = __builtin_amdgcn_mfma_f32_16x16x32_bf16(Wf[1][3], E3, acc1, 0, 0, 0); \
    const int j = (t) * 16 + l15;                                            \
    if (j < N) {                                                             \
      const float msk = mi * (float)(MJ);                                    \
      const f32x4 e40 = bf4f(R0), e41 = bf4f(R1);                            \
      float* og = oute + (size_t)j * H;                                      \
      f32x4 o0, o1;                                                          \
      _Pragma("unroll")                                                      \
      for (int r = 0; r < 4; ++r) {                                          \
        float v = acc0[r] + base4[0][r] + VX0[r];                            \
        float rr = (msk > 0.f) ? (v * sc4[0][r] + sh4[0][r]) : v;            \
        o0[r] = e40[r] + fmaxf(rr, 0.f);                                     \
        v = acc1[r] + base4[1][r] + VX1[r];                                  \
        rr = (msk > 0.f) ? (v * sc4[1][r] + sh4[1][r]) : v;                  \
        o1[r] = e41[r] + fmaxf(rr, 0.f);                                     \
      }                                                                      \
      *(f32x4*)&og[h0a] = o0;                                                \
      *(f32x4*)&og[h0b] = o1;                                                \
    }                                                                        \
    if ((t) + 2 < NT) P1_ISSUE((t) + 2, E0, E1, E2, E3, R0, R1, VX0, VX1, MJ) \
  }

__global__ __launch_bounds__(256, 2) void k_edge1f(
    const int* __restrict__ mask,
    const float* __restrict__ UeW, const float* __restrict__ Ueb,
    const float* __restrict__ ws, const unsigned short* __restrict__ ebf,
    float* __restrict__ out) {
  const int bi = blockIdx.x;
  const int b = bi / N;
  const int tid = threadIdx.x;
  const int w = tid >> 6, lane = tid & 63;
  const int l15 = lane & 15, lg = lane >> 4;
  const int hbase = w * 32;
  const int h0a = hbase + 4 * lg;          // ht=0
  const int h0b = hbase + 16 + 4 * lg;     // ht=1
  const int lgp = lg >> 1;                 // residual frag sub-row
  const int eo = 4 * (lg & 1);             // residual element offset

  const float mi = (float)mask[bi];
  float* __restrict__ oute = out + (size_t)X_SIZE + (size_t)bi * NH;

  short8 Wf[2][4];
  #pragma unroll
  for (int ht = 0; ht < 2; ++ht) {
    const float* wr = &UeW[(size_t)(hbase + ht * 16 + l15) * H + lg * 8];
    #pragma unroll
    for (int s = 0; s < 4; ++s) {
      const f32x4 u0 = *(const f32x4*)(wr + s * 32);
      const f32x4 u1 = *(const f32x4*)(wr + s * 32 + 4);
      Wf[ht][s] = pack8(u0, u1);
    }
  }
  f32x4 base4[2], sc4[2], sh4[2];
  #pragma unroll
  for (int ht = 0; ht < 2; ++ht) {
    const int h0 = hbase + ht * 16 + 4 * lg;
    const f32x4 ub = *(const f32x4*)&Ueb[h0];
    const f32x4 vx = *(const f32x4*)&ws[WS_VX + (size_t)bi * H + h0];
    base4[ht] = ub + vx;
    sc4[ht] = *(const f32x4*)&ws[WS_ESC + h0];
    sh4[ht] = *(const f32x4*)&ws[WS_ESH + h0];
  }

  short8 EA0, EA1, EA2, EA3, EB0, EB1, EB2, EB3;
  s16x4 RA0, RA1, RB0, RB1;
  f32x4 VA0, VA1, VB0, VB1;
  int MA, MB;

  P1_ISSUE(0, EA0, EA1, EA2, EA3, RA0, RA1, VA0, VA1, MA);
  P1_ISSUE(1, EB0, EB1, EB2, EB3, RB0, RB1, VB0, VB1, MB);

  for (int jt = 0; jt < NT; jt += 2) {
    P1_TILE(jt, EA0, EA1, EA2, EA3, RA0, RA1, VA0, VA1, MA);
    if (jt + 1 < NT)
      P1_TILE(jt + 1, EB0, EB1, EB2, EB3, RB0, RB1, VB0, VB1, MB);
  }
}

// ---- pass 1 (fallback, round-8 proven): recompute from f32 e via LDS ----
__global__ __launch_bounds__(256, 3) void k_edge1o(
    const float* __restrict__ e, const int* __restrict__ mask,
    const float* __restrict__ UeW, const float* __restrict__ Ueb,
    const float* __restrict__ ws, float* __restrict__ out) {
  const int bi = blockIdx.x;
  const int b = bi / N;
  const int tid = threadIdx.x;
  const int w = tid >> 6, lane = tid & 63;
  const int l15 = lane & 15, lg = lane >> 4;
  const int hbase = w * 32;

  __shared__ float lds[2][2 * 2048];
  __shared__ float mrow[N];

  const float mi = (float)mask[bi];
  const float* __restrict__ eg  = e + (size_t)bi * NH;
  const float* __restrict__ vxg = ws + WS_VX + (size_t)b * NH;

  auto stage = [&](int buf, int jt) {
    const int j0 = jt * 16;
    #pragma unroll
    for (int ii = 0; ii < 2; ++ii) {
      const int instr = 2 * w + ii;
      const int row = 2 * instr + (lane >> 5);
      const int gr = min(j0 + row, N - 1);
      const int sc16 = (lane & 31) ^ (row & 7);
      const size_t so = (size_t)gr * H + sc16 * 4;
      float* dst = &lds[buf][instr * 256];
      __builtin_amdgcn_global_load_lds(
          (const __attribute__((address_space(1))) void*)(eg + so),
          (__attribute__((address_space(3))) void*)dst, 16, 0, 0);
      __builtin_amdgcn_global_load_lds(
          (const __attribute__((address_space(1))) void*)(vxg + so),
          (__attribute__((address_space(3))) void*)(dst + 2048), 16, 0, 0);
    }
  };

  if (tid < N) mrow[tid] = (float)mask[b * N + tid];

  short8 Wf[2][4];
  #pragma unroll
  for (int ht = 0; ht < 2; ++ht) {
    const float* wr = &UeW[(size_t)(hbase + ht * 16 + l15) * H + lg * 8];
    #pragma unroll
    for (int s = 0; s < 4; ++s) {
      const f32x4 u0 = *(const f32x4*)(wr + s * 32);
      const f32x4 u1 = *(const f32x4*)(wr + s * 32 + 4);
      Wf[ht][s] = pack8(u0, u1);
    }
  }
  f32x4 base4[2], sc4[2], sh4[2];
  #pragma unroll
  for (int ht = 0; ht < 2; ++ht) {
    const int h0 = hbase + ht * 16 + 4 * lg;
    const f32x4 ub = *(const f32x4*)&Ueb[h0];
    const f32x4 vx = *(const f32x4*)&ws[WS_VX + (size_t)bi * H + h0];
    base4[ht] = ub + vx;
    sc4[ht] = *(const f32x4*)&ws[WS_ESC + h0];
    sh4[ht] = *(const f32x4*)&ws[WS_ESH + h0];
  }

  asm volatile("s_waitcnt vmcnt(0) lgkmcnt(0)" ::: "memory");
  __builtin_amdgcn_s_barrier();

  stage(0, 0);
  stage(1, 1);

  for (int jt = 0; jt < NT; ++jt) {
    if (jt == 0)      asm volatile("s_waitcnt vmcnt(4)" ::: "memory");
    else if (jt == 1) asm volatile("s_waitcnt vmcnt(6)" ::: "memory");
    else if (jt < 12) asm volatile("s_waitcnt vmcnt(8)" ::: "memory");
    else              asm volatile("s_waitcnt vmcnt(4)" ::: "memory");
    __builtin_amdgcn_s_barrier();

    const float* tp = &lds[jt & 1][0];
    short8 Ef[4];
    #pragma unroll
    for (int s = 0; s < 4; ++s) {
      const int c0 = (lg * 2 + s * 8) ^ (l15 & 7);
      const int c1 = (lg * 2 + s * 8 + 1) ^ (l15 & 7);
      const f32x4 u0 = *(const f32x4*)&tp[l15 * 128 + c0 * 4];
      const f32x4 u1 = *(const f32x4*)&tp[l15 * 128 + c1 * 4];
      Ef[s] = pack8(u0, u1);
    }
    f32x4 vx4[2], e4[2];
    #pragma unroll
    for (int ht = 0; ht < 2; ++ht) {
      const int h0 = hbase + ht * 16 + 4 * lg;
      const int ch = (h0 >> 2) ^ (l15 & 7);
      vx4[ht] = *(const f32x4*)&tp[2048 + l15 * 128 + ch * 4];
      e4[ht]  = *(const f32x4*)&tp[l15 * 128 + ch * 4];
    }

    asm volatile("s_waitcnt lgkmcnt(0)" ::: "memory");
    __builtin_amdgcn_sched_barrier(0);
    __builtin_amdgcn_s_barrier();

    if (jt + 2 < NT) stage(jt & 1, jt + 2);

    f32x4 acc[2] = {f32x4(0.f), f32x4(0.f)};
    #pragma unroll
    for (int s = 0; s < 4; ++s) {
      #pragma unroll
      for (int ht = 0; ht < 2; ++ht)
        acc[ht] = __builtin_amdgcn_mfma_f32_16x16x32_bf16(Wf[ht][s], Ef[s], acc[ht], 0, 0, 0);
    }

    const int j = jt * 16 + l15;
    if (j < N) {
      const float msk = mi * mrow[j];
      float* __restrict__ og = out + (size_t)X_SIZE + (size_t)bi * NH + (size_t)j * H;
      #pragma unroll
      for (int ht = 0; ht < 2; ++ht) {
        const int h0 = hbase + ht * 16 + 4 * lg;
        f32x4 o;
        #pragma unroll
        for (int r = 0; r < 4; ++r) {
          const float v = acc[ht][r] + base4[ht][r] + vx4[ht][r];
          const float rr = (msk > 0.f) ? (v * sc4[ht][r] + sh4[ht][r]) : v;
          o[r] = e4[ht][r] + fmaxf(rr, 0.f);
        }
        *(f32x4*)&og[h0] = o;
      }
    }
  }
}

}  // namespace

extern "C" void kernel_launch(void* const* d_in, const int* in_sizes, int n_in,
                              void* d_out, int out_size, void* d_ws, size_t ws_size,
                              hipStream_t stream) {
  const float* x    = (const float*)d_in[0];
  const float* e    = (const float*)d_in[1];
  const int*   mask = (const int*)d_in[2];
  const float* UeW  = (const float*)d_in[3];
  const float* Ueb  = (const float*)d_in[4];
  const float* VeW  = (const float*)d_in[5];
  const float* Veb  = (const float*)d_in[6];
  const float* UnW  = (const float*)d_in[7];
  const float* Unb  = (const float*)d_in[8];
  const float* VnW  = (const float*)d_in[9];
  const float* Vnb  = (const float*)d_in[10];
  const float* bng  = (const float*)d_in[11];
  const float* bnb  = (const float*)d_in[12];
  const float* beg  = (const float*)d_in[13];
  const float* beb  = (const float*)d_in[14];
  float* ws  = (float*)d_ws;
  float* out = (float*)d_out;
  unsigned short* ebf = (unsigned short*)(ws + WS_EBF);
  const bool have_ws = (ws_size >= NEED_WS_BYTES);

  hipMemsetAsync(ws + WS_ESUMS, 0, (WS_STAT_END - WS_ESUMS) * sizeof(float), stream);
  k_prep<<<BN, 128, 0, stream>>>(x, mask, VeW, Veb, UnW, Unb, VnW, Vnb, ws);
  if (have_ws)
    k_edge0<1><<<BN, 256, 0, stream>>>(e, mask, UeW, Ueb, ws, ebf, out);
  else
    k_edge0<0><<<BN, 256, 0, stream>>>(e, mask, UeW, Ueb, ws, ebf, out);
  k_stats<<<1, 256, 0, stream>>>(mask, beg, beb, bng, bnb, ws);
  k_x2<<<800, 256, 0, stream>>>(x, mask, ws, out);
  if (have_ws)
    k_edge1f<<<BN, 256, 0, stream>>>(mask, UeW, Ueb, ws, ebf, out);
  else
    k_edge1o<<<BN, 256, 0, stream>>>(e, mask, UeW, Ueb, ws, out);
}

// Round 10
// 198.568 us; speedup vs baseline: 1.0805x; 1.0805x over previous
//
#include <hip/hip_runtime.h>
#include <hip/hip_bf16.h>

namespace {

typedef __attribute__((ext_vector_type(8))) short short8;
typedef __attribute__((ext_vector_type(4))) float f32x4;

constexpr int H = 128;
constexpr int N = 200;
constexpr int BN = 1600;          // B*N
constexpr int X_SIZE = BN * H;    // 204800
constexpr int NH = N * H;         // 25600
constexpr int NT = 13;            // j-tiles of 16

// ws offsets (floats)
constexpr int WS_VX    = 0;
constexpr int WS_UX    = WS_VX + X_SIZE;
constexpr int WS_VXN   = WS_UX + X_SIZE;
constexpr int WS_XTMP  = WS_VXN + X_SIZE;
constexpr int WS_ESUMS = WS_XTMP + X_SIZE;     // 32 slots x H
constexpr int WS_ESSQS = WS_ESUMS + 32 * H;
constexpr int WS_NSUMS = WS_ESSQS + 32 * H;    // 32 slots x H
constexpr int WS_NSSQS = WS_NSUMS + 32 * H;
constexpr int WS_STAT_END = WS_NSSQS + 32 * H;
constexpr int WS_ESC   = WS_STAT_END;
constexpr int WS_ESH   = WS_ESC + H;
constexpr int WS_NSC   = WS_ESH + H;
constexpr int WS_NSH   = WS_NSC + H;

__device__ __forceinline__ unsigned short f2bf(float f) {
  __hip_bfloat16 h = __float2bfloat16(f);
  return __builtin_bit_cast(unsigned short, h);
}

__device__ __forceinline__ short8 pack8(f32x4 a, f32x4 b) {
  short8 r;
  r[0] = (short)f2bf(a[0]); r[1] = (short)f2bf(a[1]);
  r[2] = (short)f2bf(a[2]); r[3] = (short)f2bf(a[3]);
  r[4] = (short)f2bf(b[0]); r[5] = (short)f2bf(b[1]);
  r[6] = (short)f2bf(b[2]); r[7] = (short)f2bf(b[3]);
  return r;
}

// ---- node linears: Vx, Ux, Vxn (masked) ----
__global__ __launch_bounds__(128) void k_prep(
    const float* __restrict__ x, const int* __restrict__ mask,
    const float* __restrict__ VeW, const float* __restrict__ Veb,
    const float* __restrict__ UnW, const float* __restrict__ Unb,
    const float* __restrict__ VnW, const float* __restrict__ Vnb,
    float* __restrict__ ws) {
  const int bi = blockIdx.x, h = threadIdx.x;
  __shared__ float xr[H];
  xr[h] = x[bi * H + h];
  __syncthreads();
  const float mi = (float)mask[bi];
  float a0 = 0.f, a1 = 0.f, a2 = 0.f;
  #pragma unroll 4
  for (int k = 0; k < H; k += 4) {
    const float x0 = xr[k], x1 = xr[k + 1], x2 = xr[k + 2], x3 = xr[k + 3];
    float4 w;
    w = *(const float4*)&VeW[h * H + k];
    a0 += w.x * x0 + w.y * x1 + w.z * x2 + w.w * x3;
    w = *(const float4*)&UnW[h * H + k];
    a1 += w.x * x0 + w.y * x1 + w.z * x2 + w.w * x3;
    w = *(const float4*)&VnW[h * H + k];
    a2 += w.x * x0 + w.y * x1 + w.z * x2 + w.w * x3;
  }
  ws[WS_VX  + bi * H + h] = mi * (a0 + Veb[h]);
  ws[WS_UX  + bi * H + h] = mi * (a1 + Unb[h]);
  ws[WS_VXN + bi * H + h] = mi * (a2 + Vnb[h]);
}

// ---- pass 0: GEMM + edge stats + sigmoid aggregation + fused x_tmp/node stats ----
// Round-8 proven counted-vmcnt pipeline, deepened to 3 LDS buffers (depth-2
// prefetch): stage(jt+3) issued at iter jt, consumed at iter jt+3 -> ~2 tile
// phases (~1100 cy) in flight > ~900 cy HBM latency. FIFO peel (6 loads/stage):
//   jt<=10: [S_jt S_jt+1 S_jt+2] -> vmcnt(12); jt=11: vmcnt(6); jt=12: vmcnt(0).
__global__ __launch_bounds__(256, 2) void k_edge0(
    const float* __restrict__ e, const int* __restrict__ mask,
    const float* __restrict__ UeW, const float* __restrict__ Ueb,
    float* __restrict__ ws) {
  const int bi = blockIdx.x;
  const int b = bi / N;
  const int tid = threadIdx.x;
  const int w = tid >> 6, lane = tid & 63;
  const int l15 = lane & 15, lg = lane >> 4;
  const int hbase = w * 32;

  __shared__ float lds[3][3 * 2048];   // [buf][e | vx | vxn], 72 KB
  __shared__ float mrow[N];
  __shared__ float sS[H], sS2[H], sA[H];

  const float mi = (float)mask[bi];
  const float* __restrict__ eg  = e + (size_t)bi * NH;
  const float* __restrict__ vxg = ws + WS_VX  + (size_t)b * NH;
  const float* __restrict__ vng = ws + WS_VXN + (size_t)b * NH;

  // 6 global_load_lds per wave per tile (2 instr x 3 arrays), source pre-swizzled
  auto stage = [&](int buf, int jt) {
    const int j0 = jt * 16;
    #pragma unroll
    for (int ii = 0; ii < 2; ++ii) {
      const int instr = 2 * w + ii;               // 0..7
      const int row = 2 * instr + (lane >> 5);    // 0..15
      const int gr = min(j0 + row, N - 1);
      const int sc16 = (lane & 31) ^ (row & 7);   // swizzled 16B chunk
      const size_t so = (size_t)gr * H + sc16 * 4;
      float* dst = &lds[buf][instr * 256];
      __builtin_amdgcn_global_load_lds(
          (const __attribute__((address_space(1))) void*)(eg + so),
          (__attribute__((address_space(3))) void*)dst, 16, 0, 0);
      __builtin_amdgcn_global_load_lds(
          (const __attribute__((address_space(1))) void*)(vxg + so),
          (__attribute__((address_space(3))) void*)(dst + 2048), 16, 0, 0);
      __builtin_amdgcn_global_load_lds(
          (const __attribute__((address_space(1))) void*)(vng + so),
          (__attribute__((address_space(3))) void*)(dst + 4096), 16, 0, 0);
    }
  };

  // ---- register prologue (all VMEM drained before the pipeline starts) ----
  if (tid < N) mrow[tid] = (float)mask[b * N + tid];

  short8 Wf[2][4];   // A-operand: lane holds W[hbase+ht*16+l15][s*32 + lg*8 + 0..7]
  #pragma unroll
  for (int ht = 0; ht < 2; ++ht) {
    const float* wr = &UeW[(size_t)(hbase + ht * 16 + l15) * H + lg * 8];
    #pragma unroll
    for (int s = 0; s < 4; ++s) {
      const f32x4 u0 = *(const f32x4*)(wr + s * 32);
      const f32x4 u1 = *(const f32x4*)(wr + s * 32 + 4);
      Wf[ht][s] = pack8(u0, u1);
    }
  }
  f32x4 base4[2];    // Ueb + Vx_i at lane's 4 consecutive h
  #pragma unroll
  for (int ht = 0; ht < 2; ++ht) {
    const int h0 = hbase + ht * 16 + 4 * lg;
    const f32x4 ub = *(const f32x4*)&Ueb[h0];
    const f32x4 vx = *(const f32x4*)&ws[WS_VX + (size_t)bi * H + h0];
    base4[ht] = ub + vx;
  }

  asm volatile("s_waitcnt vmcnt(0) lgkmcnt(0)" ::: "memory");
  __builtin_amdgcn_s_barrier();     // mrow visible; vmcnt clean

  stage(0, 0);                       // queue: S0(6)
  stage(1, 1);                       // queue: S0 S1
  stage(2, 2);                       // queue: S0 S1 S2 (18 outstanding)

  float bnS[2][4] = {{0,0,0,0},{0,0,0,0}};
  float bnS2[2][4] = {{0,0,0,0},{0,0,0,0}};
  float ag[2][4] = {{0,0,0,0},{0,0,0,0}};

  for (int jt = 0; jt < NT; ++jt) {
    // FIFO: at top, outstanding after S_jt = S_{jt+1},S_{jt+2} (if issued)
    if (jt <= 10)      asm volatile("s_waitcnt vmcnt(12)" ::: "memory");
    else if (jt == 11) asm volatile("s_waitcnt vmcnt(6)" ::: "memory");
    else               asm volatile("s_waitcnt vmcnt(0)" ::: "memory");
    __builtin_amdgcn_s_barrier();    // all waves' stage(jt) landed

    const float* tp = &lds[jt % 3][0];
    short8 Ef[4];                    // B-operand: col j = l15, k = lg*8 + s*32 + 0..7
    #pragma unroll
    for (int s = 0; s < 4; ++s) {
      const int c0 = (lg * 2 + s * 8) ^ (l15 & 7);
      const int c1 = (lg * 2 + s * 8 + 1) ^ (l15 & 7);
      const f32x4 u0 = *(const f32x4*)&tp[l15 * 128 + c0 * 4];
      const f32x4 u1 = *(const f32x4*)&tp[l15 * 128 + c1 * 4];
      Ef[s] = pack8(u0, u1);
    }
    f32x4 vx4[2], vn4[2];
    #pragma unroll
    for (int ht = 0; ht < 2; ++ht) {
      const int h0 = hbase + ht * 16 + 4 * lg;
      const int ch = (h0 >> 2) ^ (l15 & 7);
      vx4[ht] = *(const f32x4*)&tp[2048 + l15 * 128 + ch * 4];
      vn4[ht] = *(const f32x4*)&tp[4096 + l15 * 128 + ch * 4];
    }

    asm volatile("s_waitcnt lgkmcnt(0)" ::: "memory");
    __builtin_amdgcn_sched_barrier(0);
    __builtin_amdgcn_s_barrier();    // all waves done reading lds[jt%3]

    if (jt + 3 < NT) stage(jt % 3, jt + 3);   // overwrite freed buffer

    f32x4 acc[2] = {f32x4(0.f), f32x4(0.f)};
    #pragma unroll
    for (int s = 0; s < 4; ++s) {
      #pragma unroll
      for (int ht = 0; ht < 2; ++ht)   // D[h][j]: col j = l15, row h = hbase+ht*16+4*lg+r
        acc[ht] = __builtin_amdgcn_mfma_f32_16x16x32_bf16(Wf[ht][s], Ef[s], acc[ht], 0, 0, 0);
    }

    // epilogue: registers only
    const int j = jt * 16 + l15;
    const float msk = (j < N) ? mi * mrow[j < N ? j : 0] : 0.f;
    #pragma unroll
    for (int ht = 0; ht < 2; ++ht) {
      #pragma unroll
      for (int r = 0; r < 4; ++r) {
        const float v = acc[ht][r] + base4[ht][r] + vx4[ht][r];
        bnS[ht][r]  += msk * v;
        bnS2[ht][r] += msk * v * v;
        const float sg = __builtin_amdgcn_rcpf(1.f + __expf(-v));
        ag[ht][r] += msk * sg * vn4[ht][r];
      }
    }
  }

  // reduce stats over j-lanes (l15: xor 1,2,4,8), then one writer per h
  #pragma unroll
  for (int ht = 0; ht < 2; ++ht) {
    #pragma unroll
    for (int r = 0; r < 4; ++r) {
      #pragma unroll
      for (int mm = 1; mm <= 8; mm <<= 1) {
        bnS[ht][r]  += __shfl_xor(bnS[ht][r], mm);
        bnS2[ht][r] += __shfl_xor(bnS2[ht][r], mm);
        ag[ht][r]   += __shfl_xor(ag[ht][r], mm);
      }
    }
  }
  if (l15 == 0) {
    #pragma unroll
    for (int ht = 0; ht < 2; ++ht) {
      #pragma unroll
      for (int r = 0; r < 4; ++r) {
        const int h = hbase + ht * 16 + 4 * lg + r;   // disjoint across writers
        sS[h] = bnS[ht][r]; sS2[h] = bnS2[ht][r]; sA[h] = ag[ht][r];
      }
    }
  }
  __syncthreads();
  if (tid < H) {
    const int slot = (bi & 31) * H + tid;
    atomicAdd(&ws[WS_ESUMS + slot], sS[tid]);
    atomicAdd(&ws[WS_ESSQS + slot], sS2[tid]);
    // fused x_tmp = Ux + agg, plus node BN partials
    const float v = ws[WS_UX + (size_t)bi * H + tid] + sA[tid];
    ws[WS_XTMP + (size_t)bi * H + tid] = v;
    atomicAdd(&ws[WS_NSUMS + slot], mi * v);
    atomicAdd(&ws[WS_NSSQS + slot], mi * v * v);
  }
}

// ---- counts + finalize BN scale/shift for edge and node ----
__global__ void k_stats(const int* __restrict__ mask,
                        const float* __restrict__ beg, const float* __restrict__ beb,
                        const float* __restrict__ bng, const float* __restrict__ bnb,
                        float* __restrict__ ws) {
  __shared__ float sb[8];
  const int t = threadIdx.x;          // 256 threads
  const int b = t >> 5, li = t & 31;
  float s = 0.f;
  for (int i = li; i < N; i += 32) s += (float)mask[b * N + i];
  #pragma unroll
  for (int o = 16; o >= 1; o >>= 1) s += __shfl_down(s, o, 32);
  if (li == 0) sb[b] = s;
  __syncthreads();
  if (t < H) {
    float cn = 0.f, ce = 0.f;
    #pragma unroll
    for (int bb = 0; bb < 8; ++bb) { cn += sb[bb]; ce += sb[bb] * sb[bb]; }
    ce = fmaxf(ce, 1.f); cn = fmaxf(cn, 1.f);
    float es = 0.f, es2 = 0.f, ns = 0.f, ns2 = 0.f;
    #pragma unroll 4
    for (int k = 0; k < 32; ++k) {
      es  += ws[WS_ESUMS + k * H + t];
      es2 += ws[WS_ESSQS + k * H + t];
      ns  += ws[WS_NSUMS + k * H + t];
      ns2 += ws[WS_NSSQS + k * H + t];
    }
    const float me = es / ce;
    const float ve = fmaxf(es2 / ce - me * me, 0.f);
    const float se = rsqrtf(ve + 1e-5f) * beg[t];
    ws[WS_ESC + t] = se;
    ws[WS_ESH + t] = beb[t] - me * se;
    const float mn = ns / cn;
    const float vn = fmaxf(ns2 / cn - mn * mn, 0.f);
    const float sn = rsqrtf(vn + 1e-5f) * bng[t];
    ws[WS_NSC + t] = sn;
    ws[WS_NSH + t] = bnb[t] - mn * sn;
  }
}

// ---- x_new = x + relu(masked BN(x_tmp)) ----
__global__ void k_x2(const float* __restrict__ x, const int* __restrict__ mask,
                     const float* __restrict__ ws, float* __restrict__ out) {
  const int idx = blockIdx.x * 256 + threadIdx.x;
  if (idx >= X_SIZE) return;
  const int h = idx & 127, bi = idx >> 7;
  const float v = ws[WS_XTMP + idx];
  const float r = (mask[bi] != 0) ? (v * ws[WS_NSC + h] + ws[WS_NSH + h]) : v;
  out[idx] = x[idx] + fmaxf(r, 0.f);
}

// ---- pass 1: recompute e_tmp, normalize + residual + write ----
// Same 3-buffer depth-2 pipeline; 4 loads/stage + 2 stores/iter. FIFO peel
// (outstanding AFTER S_jt at top of iter jt):
//   jt=0: S1 S2 = 8           jt=1: S2 S3 st0 = 10
//   jt=2: S3 st0 S4 st1 = 12  jt=3..10: st(jt-3) S_{jt+1} st(jt-2) S_{jt+2} st(jt-1) = 14
//   jt=11: st8 S12 st9 st10 = 10   jt=12: st9 st10 st11 = 6
__global__ __launch_bounds__(256, 2) void k_edge1(
    const float* __restrict__ e, const int* __restrict__ mask,
    const float* __restrict__ UeW, const float* __restrict__ Ueb,
    const float* __restrict__ ws, float* __restrict__ out) {
  const int bi = blockIdx.x;
  const int b = bi / N;
  const int tid = threadIdx.x;
  const int w = tid >> 6, lane = tid & 63;
  const int l15 = lane & 15, lg = lane >> 4;
  const int hbase = w * 32;

  __shared__ float lds[3][2 * 2048];   // [buf][e | vx], 48 KB
  __shared__ float mrow[N];

  const float mi = (float)mask[bi];
  const float* __restrict__ eg  = e + (size_t)bi * NH;
  const float* __restrict__ vxg = ws + WS_VX + (size_t)b * NH;

  auto stage = [&](int buf, int jt) {
    const int j0 = jt * 16;
    #pragma unroll
    for (int ii = 0; ii < 2; ++ii) {
      const int instr = 2 * w + ii;
      const int row = 2 * instr + (lane >> 5);
      const int gr = min(j0 + row, N - 1);
      const int sc16 = (lane & 31) ^ (row & 7);
      const size_t so = (size_t)gr * H + sc16 * 4;
      float* dst = &lds[buf][instr * 256];
      __builtin_amdgcn_global_load_lds(
          (const __attribute__((address_space(1))) void*)(eg + so),
          (__attribute__((address_space(3))) void*)dst, 16, 0, 0);
      __builtin_amdgcn_global_load_lds(
          (const __attribute__((address_space(1))) void*)(vxg + so),
          (__attribute__((address_space(3))) void*)(dst + 2048), 16, 0, 0);
    }
  };

  // ---- register prologue ----
  if (tid < N) mrow[tid] = (float)mask[b * N + tid];

  short8 Wf[2][4];
  #pragma unroll
  for (int ht = 0; ht < 2; ++ht) {
    const float* wr = &UeW[(size_t)(hbase + ht * 16 + l15) * H + lg * 8];
    #pragma unroll
    for (int s = 0; s < 4; ++s) {
      const f32x4 u0 = *(const f32x4*)(wr + s * 32);
      const f32x4 u1 = *(const f32x4*)(wr + s * 32 + 4);
      Wf[ht][s] = pack8(u0, u1);
    }
  }
  f32x4 base4[2], sc4[2], sh4[2];
  #pragma unroll
  for (int ht = 0; ht < 2; ++ht) {
    const int h0 = hbase + ht * 16 + 4 * lg;
    const f32x4 ub = *(const f32x4*)&Ueb[h0];
    const f32x4 vx = *(const f32x4*)&ws[WS_VX + (size_t)bi * H + h0];
    base4[ht] = ub + vx;
    sc4[ht] = *(const f32x4*)&ws[WS_ESC + h0];
    sh4[ht] = *(const f32x4*)&ws[WS_ESH + h0];
  }

  asm volatile("s_waitcnt vmcnt(0) lgkmcnt(0)" ::: "memory");
  __builtin_amdgcn_s_barrier();

  stage(0, 0);
  stage(1, 1);
  stage(2, 2);

  for (int jt = 0; jt < NT; ++jt) {
    if (jt == 0)       asm volatile("s_waitcnt vmcnt(8)" ::: "memory");
    else if (jt == 1)  asm volatile("s_waitcnt vmcnt(10)" ::: "memory");
    else if (jt == 2)  asm volatile("s_waitcnt vmcnt(12)" ::: "memory");
    else if (jt <= 10) asm volatile("s_waitcnt vmcnt(14)" ::: "memory");
    else if (jt == 11) asm volatile("s_waitcnt vmcnt(10)" ::: "memory");
    else               asm volatile("s_waitcnt vmcnt(6)" ::: "memory");
    __builtin_amdgcn_s_barrier();

    const float* tp = &lds[jt % 3][0];
    short8 Ef[4];
    #pragma unroll
    for (int s = 0; s < 4; ++s) {
      const int c0 = (lg * 2 + s * 8) ^ (l15 & 7);
      const int c1 = (lg * 2 + s * 8 + 1) ^ (l15 & 7);
      const f32x4 u0 = *(const f32x4*)&tp[l15 * 128 + c0 * 4];
      const f32x4 u1 = *(const f32x4*)&tp[l15 * 128 + c1 * 4];
      Ef[s] = pack8(u0, u1);
    }
    f32x4 vx4[2], e4[2];
    #pragma unroll
    for (int ht = 0; ht < 2; ++ht) {
      const int h0 = hbase + ht * 16 + 4 * lg;
      const int ch = (h0 >> 2) ^ (l15 & 7);
      vx4[ht] = *(const f32x4*)&tp[2048 + l15 * 128 + ch * 4];
      e4[ht]  = *(const f32x4*)&tp[l15 * 128 + ch * 4];   // residual
    }

    asm volatile("s_waitcnt lgkmcnt(0)" ::: "memory");
    __builtin_amdgcn_sched_barrier(0);
    __builtin_amdgcn_s_barrier();

    if (jt + 3 < NT) stage(jt % 3, jt + 3);

    f32x4 acc[2] = {f32x4(0.f), f32x4(0.f)};
    #pragma unroll
    for (int s = 0; s < 4; ++s) {
      #pragma unroll
      for (int ht = 0; ht < 2; ++ht)
        acc[ht] = __builtin_amdgcn_mfma_f32_16x16x32_bf16(Wf[ht][s], Ef[s], acc[ht], 0, 0, 0);
    }

    const int j = jt * 16 + l15;
    if (j < N) {
      const float msk = mi * mrow[j];
      float* __restrict__ og = out + (size_t)X_SIZE + (size_t)bi * NH + (size_t)j * H;
      #pragma unroll
      for (int ht = 0; ht < 2; ++ht) {
        const int h0 = hbase + ht * 16 + 4 * lg;
        f32x4 o;
        #pragma unroll
        for (int r = 0; r < 4; ++r) {
          const float v = acc[ht][r] + base4[ht][r] + vx4[ht][r];
          const float rr = (msk > 0.f) ? (v * sc4[ht][r] + sh4[ht][r]) : v;
          o[r] = e4[ht][r] + fmaxf(rr, 0.f);
        }
        *(f32x4*)&og[h0] = o;
      }
    }
  }
}

}  // namespace

extern "C" void kernel_launch(void* const* d_in, const int* in_sizes, int n_in,
                              void* d_out, int out_size, void* d_ws, size_t ws_size,
                              hipStream_t stream) {
  const float* x    = (const float*)d_in[0];
  const float* e    = (const float*)d_in[1];
  const int*   mask = (const int*)d_in[2];
  const float* UeW  = (const float*)d_in[3];
  const float* Ueb  = (const float*)d_in[4];
  const float* VeW  = (const float*)d_in[5];
  const float* Veb  = (const float*)d_in[6];
  const float* UnW  = (const float*)d_in[7];
  const float* Unb  = (const float*)d_in[8];
  const float* VnW  = (const float*)d_in[9];
  const float* Vnb  = (const float*)d_in[10];
  const float* bng  = (const float*)d_in[11];
  const float* bnb  = (const float*)d_in[12];
  const float* beg  = (const float*)d_in[13];
  const float* beb  = (const float*)d_in[14];
  float* ws  = (float*)d_ws;
  float* out = (float*)d_out;

  // zero the slotted stat accumulators (contiguous 4 x 32 x H region)
  hipMemsetAsync(ws + WS_ESUMS, 0, (WS_STAT_END - WS_ESUMS) * sizeof(float), stream);
  k_prep<<<BN, 128, 0, stream>>>(x, mask, VeW, Veb, UnW, Unb, VnW, Vnb, ws);
  k_edge0<<<BN, 256, 0, stream>>>(e, mask, UeW, Ueb, ws);
  k_stats<<<1, 256, 0, stream>>>(mask, beg, beb, bng, bnb, ws);
  k_x2<<<800, 256, 0, stream>>>(x, mask, ws, out);
  k_edge1<<<BN, 256, 0, stream>>>(e, mask, UeW, Ueb, ws, out);
}